// Round 1
// baseline (1869.101 us; speedup 1.0000x reference)
//
#include <hip/hip_runtime.h>
#include <cstdint>
#include <cstddef>

typedef unsigned short u16;
typedef __attribute__((__ext_vector_type__(8))) __bf16 bf16x8;
typedef __attribute__((__ext_vector_type__(4))) float f32x4;
typedef __attribute__((__ext_vector_type__(8))) unsigned short u16x8;

#define DEVI __device__ __forceinline__

constexpr int Bb = 2, Ss = 1024, Dd = 1024, Hh = 16;
constexpr int CKVc = 256, DFFc = 2816, Lc = 4, Vc = 32000;
constexpr int Mm = Bb * Ss;       // 2048 rows in the "token" dim
constexpr int QKD = 128;          // padded q/k head dim (96 -> 128, zero pad)
constexpr float EPSF = 1.1920929e-07f;
constexpr float NEG = -1e30f;
constexpr float QSCALE = 0.10206207261596577f; // 1/sqrt(96)
constexpr float LOG1E4_16 = 9.210340371976184f / 16.f;

DEVI u16 f2b(float f) {
  union { float f; uint32_t u; } a; a.f = f;
  uint32_t r = a.u + 0x7FFFu + ((a.u >> 16) & 1u);
  return (u16)(r >> 16);
}
DEVI float b2f(u16 h) {
  union { uint32_t u; float f; } a; a.u = ((uint32_t)h) << 16; return a.f;
}

// ---------------- fp32 -> bf16 transposed weight conversion (K x N -> Npad x K)
__global__ void k_wcvt(const float* __restrict__ in, u16* __restrict__ out,
                       int K, int N, int Npad) {
  __shared__ float t[32][33];
  int bk = blockIdx.x * 32, bn = blockIdx.y * 32;
  int tx = threadIdx.x, ty = threadIdx.y;
  #pragma unroll
  for (int i = ty; i < 32; i += 8) {
    int n = bn + tx;
    t[i][tx] = (n < N) ? in[(size_t)(bk + i) * N + n] : 0.f;
  }
  __syncthreads();
  #pragma unroll
  for (int i = ty; i < 32; i += 8) {
    int n = bn + i;
    out[(size_t)n * K + bk + tx] = f2b(t[tx][i]);
  }
}

// ---------------- embedding gather
__global__ void k_embed(const int* __restrict__ tok, const float* __restrict__ emb,
                        float* __restrict__ h) {
  int m = blockIdx.x;
  int t = tok[m];
  const float4* src = (const float4*)(emb + (size_t)t * Dd);
  float4* dst = (float4*)(h + (size_t)m * Dd);
  dst[threadIdx.x] = src[threadIdx.x];
}

// ---------------- rmsnorm: f32 (stride inStride) -> bf16 (stride K)
__global__ void k_rms(const float* __restrict__ in, int inStride,
                      const float* __restrict__ w, u16* __restrict__ out, int K) {
  int m = blockIdx.x;
  const float* x = in + (size_t)m * inStride;
  float ss = 0.f;
  for (int i = threadIdx.x; i < K; i += 256) { float v = x[i]; ss += v * v; }
  #pragma unroll
  for (int off = 32; off; off >>= 1) ss += __shfl_xor(ss, off);
  __shared__ float red[4];
  if ((threadIdx.x & 63) == 0) red[threadIdx.x >> 6] = ss;
  __syncthreads();
  float r = rsqrtf((red[0] + red[1] + red[2] + red[3]) / (float)K + EPSF);
  for (int i = threadIdx.x; i < K; i += 256)
    out[(size_t)m * K + i] = f2b(x[i] * r * w[i]);
}

// ---------------- build Q (rope on cols 64..95, *QSCALE, pad to 128)
__global__ void k_buildq(const float* __restrict__ qf, u16* __restrict__ Q) {
  int s = blockIdx.x, bh = blockIdx.y;
  int b = bh >> 4, h = bh & 15;
  int d = threadIdx.x;
  const float* row = qf + (size_t)(b * Ss + s) * (Hh * 96) + h * 96;
  float v = 0.f;
  if (d < 64) v = row[d];
  else if (d < 96) {
    int j = d - 64;
    int jj = j & 15;
    float theta = expf(-(float)jj * LOG1E4_16);
    float ang = (float)s * theta;
    float x = row[64 + j];
    float o = row[64 + (j ^ 16)];
    v = x * cosf(ang) + ((j < 16) ? -o : o) * sinf(ang);
  }
  Q[((size_t)bh * Ss + s) * QKD + d] = f2b(v * QSCALE);
}

// ---------------- build K (k from kv, roped k_rope broadcast over heads)
__global__ void k_buildk(const float* __restrict__ kv, const float* __restrict__ ckv,
                         u16* __restrict__ Kb) {
  int s = blockIdx.x, bh = blockIdx.y;
  int b = bh >> 4, h = bh & 15;
  int d = threadIdx.x;
  int m = b * Ss + s;
  float v = 0.f;
  if (d < 64) v = kv[(size_t)m * 2048 + h * 128 + d];
  else if (d < 96) {
    int j = d - 64;
    int jj = j & 15;
    float theta = expf(-(float)jj * LOG1E4_16);
    float ang = (float)s * theta;
    const float* rr = ckv + (size_t)m * 288 + 256;
    float x = rr[j];
    float o = rr[j ^ 16];
    v = x * cosf(ang) + ((j < 16) ? -o : o) * sinf(ang);
  }
  Kb[((size_t)bh * Ss + s) * QKD + d] = f2b(v);
}

// ---------------- build V^T (per head: [128 pad][1024]), bf16
__global__ void k_buildvt(const float* __restrict__ kv, u16* __restrict__ Vt) {
  __shared__ float t[32][33];
  int bh = blockIdx.x, s0 = blockIdx.y * 32, d0 = blockIdx.z * 32;
  int b = bh >> 4, h = bh & 15;
  int tx = threadIdx.x, ty = threadIdx.y;
  #pragma unroll
  for (int i = ty; i < 32; i += 8) {
    int s = s0 + i, d = d0 + tx;
    t[i][tx] = (d < 64) ? kv[(size_t)(b * Ss + s) * 2048 + h * 128 + 64 + d] : 0.f;
  }
  __syncthreads();
  #pragma unroll
  for (int i = ty; i < 32; i += 8) {
    int d = d0 + i, s = s0 + tx;
    Vt[((size_t)bh * 128 + d) * Ss + s] = f2b(t[tx][i]);
  }
}

// ---------------- in-place row softmax over 1024 bf16 scores (wave per row)
__global__ void k_softmax(u16* __restrict__ sc) {
  int row = blockIdx.x * 4 + (threadIdx.x >> 6);
  int lane = threadIdx.x & 63;
  u16* p = sc + (size_t)row * 1024;
  u16x8 h0 = *(const u16x8*)(p + lane * 8);
  u16x8 h1 = *(const u16x8*)(p + 512 + lane * 8);
  float v[16];
  #pragma unroll
  for (int i = 0; i < 8; i++) { v[i] = b2f(h0[i]); v[8 + i] = b2f(h1[i]); }
  float mx = v[0];
  #pragma unroll
  for (int i = 1; i < 16; i++) mx = fmaxf(mx, v[i]);
  #pragma unroll
  for (int off = 32; off; off >>= 1) mx = fmaxf(mx, __shfl_xor(mx, off));
  float sum = 0.f;
  #pragma unroll
  for (int i = 0; i < 16; i++) { v[i] = __expf(v[i] - mx); sum += v[i]; }
  #pragma unroll
  for (int off = 32; off; off >>= 1) sum += __shfl_xor(sum, off);
  float inv = 1.f / sum;
  #pragma unroll
  for (int i = 0; i < 8; i++) { h0[i] = f2b(v[i] * inv); h1[i] = f2b(v[8 + i] * inv); }
  *(u16x8*)(p + lane * 8) = h0;
  *(u16x8*)(p + 512 + lane * 8) = h1;
}

// ---------------- bf16 MFMA GEMM, A: MxK row-major, Bt: Npad x K row-major
// MODE 0: f32 C = acc + bias            (ldc = N, store clipped to N)
// MODE 1: f32 C += acc + bias           (residual into h)
// MODE 2: bf16 scores, causal mask, batched (ldc=1024), early-out masked tiles
// MODE 3: bf16 PV -> attn scatter [(b*S+row)*D + h*64 + col], col < 64
#define GAS __attribute__((address_space(1)))
#define LAS __attribute__((address_space(3)))
DEVI void gll16(const void* g, void* l) {
  __builtin_amdgcn_global_load_lds((GAS const void*)g, (LAS void*)l, 16, 0, 0);
}

template <int MODE>
__global__ __launch_bounds__(256) void k_gemm(
    const u16* __restrict__ A, const u16* __restrict__ Bt,
    const float* __restrict__ bias, void* __restrict__ C,
    int N, int K, long sA, long sB, long sC) {
  __shared__ u16 lA[128 * 32];
  __shared__ u16 lB[128 * 32];
  const int tid = threadIdx.x;
  const int bx = blockIdx.x, by = blockIdx.y, bz = blockIdx.z;
  const long m0 = (long)bx * 128, n0 = (long)by * 128;

  if (MODE == 2 && by > bx) {  // fully above diagonal: all masked
    u16* out = (u16*)C + (size_t)bz * sC;
    u16 nv = f2b(NEG);
    for (int idx = tid; idx < 128 * 128; idx += 256) {
      long r = m0 + (idx >> 7), c = n0 + (idx & 127);
      out[r * 1024 + c] = nv;
    }
    return;
  }

  const u16* Az = A + (size_t)bz * sA;
  const u16* Bz = Bt + (size_t)bz * sB;
  const int srow = tid >> 2;
  const int scol = (tid & 3) << 3;
  const u16* a0 = Az + (m0 + srow) * (long)K + scol;
  const u16* b0 = Bz + (n0 + srow) * (long)K + scol;
  const long rstep = 64L * K;

  const int lane = tid & 63, wid = tid >> 6;
  const int wm = (wid >> 1) * 64, wn = (wid & 1) * 64;
  const int fr = lane & 15, kg = (lane >> 4) * 8;

  f32x4 acc[4][4] = {};

  for (int kk = 0; kk < K; kk += 32) {
    gll16(a0 + kk, lA + tid * 8);
    gll16(a0 + rstep + kk, lA + 2048 + tid * 8);
    gll16(b0 + kk, lB + tid * 8);
    gll16(b0 + rstep + kk, lB + 2048 + tid * 8);
    __syncthreads();
    bf16x8 af[4], bfr[4];
    #pragma unroll
    for (int i = 0; i < 4; i++) af[i] = *(const bf16x8*)&lA[(wm + i * 16 + fr) * 32 + kg];
    #pragma unroll
    for (int i = 0; i < 4; i++) bfr[i] = *(const bf16x8*)&lB[(wn + i * 16 + fr) * 32 + kg];
    #pragma unroll
    for (int i = 0; i < 4; i++)
      #pragma unroll
      for (int j = 0; j < 4; j++)
        acc[i][j] = __builtin_amdgcn_mfma_f32_16x16x32_bf16(af[i], bfr[j], acc[i][j], 0, 0, 0);
    __syncthreads();
  }

  const int rb = wm + ((lane >> 4) << 2);
  const int cb = wn + (lane & 15);
  #pragma unroll
  for (int j = 0; j < 4; j++) {
    long gcol = n0 + cb + j * 16;
    float bs = 0.f;
    if ((MODE == 0 || MODE == 1) && gcol < N) bs = bias[gcol];
    #pragma unroll
    for (int i = 0; i < 4; i++) {
      #pragma unroll
      for (int r = 0; r < 4; r++) {
        long grow = m0 + rb + i * 16 + r;
        float val = acc[i][j][r];
        if (MODE == 0) {
          if (gcol < N) ((float*)C)[grow * N + gcol] = val + bs;
        } else if (MODE == 1) {
          if (gcol < N) { float* p = (float*)C + grow * N + gcol; *p += val + bs; }
        } else if (MODE == 2) {
          u16* out = (u16*)C + (size_t)bz * sC;
          out[grow * 1024 + gcol] = f2b((gcol <= grow) ? val : NEG);
        } else {
          if (gcol < 64) {
            int b = bz >> 4, h = bz & 15;
            ((u16*)C)[((size_t)(b * Ss) + grow) * Dd + h * 64 + gcol] = f2b(val);
          }
        }
      }
    }
  }
}

// ---------------- silu gate: uv (2048 x 5632 f32) -> gated bf16 (2048 x 2816)
__global__ void k_silu(const float* __restrict__ uv, u16* __restrict__ g) {
  int n = blockIdx.x * 256 + threadIdx.x;
  int m = blockIdx.y;
  float u = uv[(size_t)m * 5632 + n];
  float x = uv[(size_t)m * 5632 + 2816 + n];
  float sg = 1.f / (1.f + expf(-x));
  g[(size_t)m * 2816 + n] = f2b(u * x * sg);
}

extern "C" void kernel_launch(void* const* d_in, const int* in_sizes, int n_in,
                              void* d_out, int out_size, void* d_ws, size_t ws_size,
                              hipStream_t stream) {
  (void)in_sizes; (void)n_in; (void)out_size; (void)ws_size;
  const int*   tokens    = (const int*)  d_in[0];
  const float* embed     = (const float*)d_in[1];
  const float* w_kv_down = (const float*)d_in[2];
  const float* b_kv_down = (const float*)d_in[3];
  const float* w_q_down  = (const float*)d_in[4];
  const float* b_q_down  = (const float*)d_in[5];
  const float* w_kv_up   = (const float*)d_in[6];
  const float* b_kv_up   = (const float*)d_in[7];
  const float* w_q_up    = (const float*)d_in[8];
  const float* b_q_up    = (const float*)d_in[9];
  const float* w_o       = (const float*)d_in[10];
  const float* b_o       = (const float*)d_in[11];
  const float* kv_norm_w = (const float*)d_in[12];
  const float* q_norm_w  = (const float*)d_in[13];
  const float* norm1_w   = (const float*)d_in[14];
  const float* norm2_w   = (const float*)d_in[15];
  const float* w_in      = (const float*)d_in[16];
  const float* b_in      = (const float*)d_in[17];
  const float* w_out     = (const float*)d_in[18];
  const float* b_out     = (const float*)d_in[19];
  const float* norm_f_w  = (const float*)d_in[20];
  const float* w_head    = (const float*)d_in[21];
  const float* b_head    = (const float*)d_in[22];

  char* base = (char*)d_ws;
  size_t off = 0;
  auto alloc = [&](size_t bytes) -> void* {
    void* p = base + off;
    off += (bytes + 255) & ~(size_t)255;
    return p;
  };
  // shared per-layer transposed-weight arena (head needs the most: 32000x1024 bf16)
  u16* warena = (u16*)alloc((size_t)32000 * 1024 * 2);
  // per-layer offsets inside arena (elements)
  u16* wT_kvdown = warena;                         // 384 x 1024
  u16* wT_kvup   = wT_kvdown + 384 * 1024;         // 2048 x 256
  u16* wT_qdown  = wT_kvup   + 2048 * 256;         // 384 x 1024
  u16* wT_qup    = wT_qdown  + 384 * 1024;         // 1536 x 384
  u16* wT_o      = wT_qup    + 1536 * 384;         // 1024 x 1024
  u16* wT_in     = wT_o      + 1024 * 1024;        // 5632 x 1024
  u16* wT_out    = wT_in     + 5632 * 1024;        // 1024 x 2816

  float* h    = (float*)alloc((size_t)Mm * 1024 * 4);
  u16*   xn   = (u16*)  alloc((size_t)Mm * 1024 * 2);
  float* ckv  = (float*)alloc((size_t)Mm * 288 * 4);
  u16*   ckvn = (u16*)  alloc((size_t)Mm * 256 * 2);
  float* kv   = (float*)alloc((size_t)Mm * 2048 * 4);
  float* qd   = (float*)alloc((size_t)Mm * 384 * 4);
  u16*   qdn  = (u16*)  alloc((size_t)Mm * 384 * 2);
  float* qf   = (float*)alloc((size_t)Mm * 1536 * 4);
  u16*   Qb   = (u16*)  alloc((size_t)32 * 1024 * QKD * 2);
  u16*   Kb   = (u16*)  alloc((size_t)32 * 1024 * QKD * 2);
  u16*   Vt   = (u16*)  alloc((size_t)32 * 128 * 1024 * 2);
  // scores (32*1024*1024 bf16 = 67MB) aliased with uv (2048*5632 f32 = 46MB):
  // lifetimes are disjoint within a layer (scores: QK->softmax->PV; uv: FFN).
  void* bigbuf = alloc((size_t)32 * 1024 * 1024 * 2);
  u16*   sc   = (u16*)bigbuf;
  float* uvb  = (float*)bigbuf;
  u16*   attn = (u16*)  alloc((size_t)Mm * 1024 * 2);
  u16*   gate = (u16*)  alloc((size_t)Mm * 2816 * 2);

  dim3 tb(32, 8);
  auto cvt = [&](const float* src, u16* dst, int K, int N, int Npad) {
    dim3 gg(K / 32, Npad / 32);
    k_wcvt<<<gg, tb, 0, stream>>>(src, dst, K, N, Npad);
  };

  k_embed<<<Mm, 256, 0, stream>>>(tokens, embed, h);

  for (int l = 0; l < Lc; l++) {
    // convert this layer's weights (transposed, bf16, N-padded)
    cvt(w_kv_down + (size_t)l * 1024 * 288,  wT_kvdown, 1024, 288, 384);
    cvt(w_kv_up   + (size_t)l * 256 * 2048,  wT_kvup,   256, 2048, 2048);
    cvt(w_q_down  + (size_t)l * 1024 * 384,  wT_qdown,  1024, 384, 384);
    cvt(w_q_up    + (size_t)l * 384 * 1536,  wT_qup,    384, 1536, 1536);
    cvt(w_o       + (size_t)l * 1024 * 1024, wT_o,      1024, 1024, 1024);
    cvt(w_in      + (size_t)l * 1024 * 5632, wT_in,     1024, 5632, 5632);
    cvt(w_out     + (size_t)l * 2816 * 1024, wT_out,    2816, 1024, 1024);

    k_rms<<<Mm, 256, 0, stream>>>(h, 1024, norm1_w + l * 1024, xn, 1024);
    k_gemm<0><<<dim3(16, 3, 1), 256, 0, stream>>>(xn, wT_kvdown, b_kv_down + l * 288,
                                                  ckv, 288, 1024, 0, 0, 0);
    k_rms<<<Mm, 256, 0, stream>>>(ckv, 288, kv_norm_w + l * 256, ckvn, 256);
    k_gemm<0><<<dim3(16, 16, 1), 256, 0, stream>>>(ckvn, wT_kvup, b_kv_up + l * 2048,
                                                   kv, 2048, 256, 0, 0, 0);
    k_gemm<0><<<dim3(16, 3, 1), 256, 0, stream>>>(xn, wT_qdown, b_q_down + l * 384,
                                                  qd, 384, 1024, 0, 0, 0);
    k_rms<<<Mm, 256, 0, stream>>>(qd, 384, q_norm_w + l * 384, qdn, 384);
    k_gemm<0><<<dim3(16, 12, 1), 256, 0, stream>>>(qdn, wT_qup, b_q_up + l * 1536,
                                                   qf, 1536, 384, 0, 0, 0);
    k_buildq<<<dim3(Ss, 32), 128, 0, stream>>>(qf, Qb);
    k_buildk<<<dim3(Ss, 32), 128, 0, stream>>>(kv, ckv, Kb);
    k_buildvt<<<dim3(32, 32, 4), tb, 0, stream>>>(kv, Vt);
    // scores: per (b,h) 1024x1024, K=128 (padded), causal mask, Q pre-scaled
    k_gemm<2><<<dim3(8, 8, 32), 256, 0, stream>>>(Qb, Kb, nullptr, sc,
                                                  1024, 128, 1024L * 128, 1024L * 128,
                                                  1024L * 1024);
    k_softmax<<<(32 * 1024) / 4, 256, 0, stream>>>(sc);
    // PV: per (b,h) 1024x64, K=1024; epilogue scatters into (B,S,H*64)
    k_gemm<3><<<dim3(8, 1, 32), 256, 0, stream>>>(sc, Vt, nullptr, attn,
                                                  64, 1024, 1024L * 1024, 128L * 1024, 0);
    k_gemm<1><<<dim3(16, 8, 1), 256, 0, stream>>>(attn, wT_o, b_o + l * 1024,
                                                  h, 1024, 1024, 0, 0, 0);
    k_rms<<<Mm, 256, 0, stream>>>(h, 1024, norm2_w + l * 1024, xn, 1024);
    k_gemm<0><<<dim3(16, 44, 1), 256, 0, stream>>>(xn, wT_in, b_in + l * 5632,
                                                   uvb, 5632, 1024, 0, 0, 0);
    k_silu<<<dim3(11, Mm), 256, 0, stream>>>(uvb, gate);
    k_gemm<1><<<dim3(16, 8, 1), 256, 0, stream>>>(gate, wT_out, b_out + l * 1024,
                                                  h, 1024, 2816, 0, 0, 0);
  }

  k_rms<<<Mm, 256, 0, stream>>>(h, 1024, norm_f_w, xn, 1024);
  cvt(w_head, warena, 1024, 32000, 32000);
  k_gemm<0><<<dim3(16, 250, 1), 256, 0, stream>>>(xn, warena, b_head,
                                                  (float*)d_out, 32000, 1024, 0, 0, 0);
}

// Round 2
// 1756.579 us; speedup vs baseline: 1.0641x; 1.0641x over previous
//
#include <hip/hip_runtime.h>
#include <cstdint>
#include <cstddef>

typedef unsigned short u16;
typedef __attribute__((__ext_vector_type__(8))) __bf16 bf16x8;
typedef __attribute__((__ext_vector_type__(4))) float f32x4;
typedef __attribute__((__ext_vector_type__(8))) unsigned short u16x8;

#define DEVI __device__ __forceinline__

constexpr int Bb = 2, Ss = 1024, Dd = 1024, Hh = 16;
constexpr int Mm = Bb * Ss;       // 2048 token rows
constexpr int QKD = 128;          // padded q/k head dim (96 -> 128, zero pad)
constexpr float EPSF = 1.1920929e-07f;
constexpr float NEG = -1e30f;
constexpr float QSCALE = 0.10206207261596577f; // 1/sqrt(96)
constexpr float LOG1E4_16 = 9.210340371976184f / 16.f;

DEVI u16 f2b(float f) {
  union { float f; uint32_t u; } a; a.f = f;
  uint32_t r = a.u + 0x7FFFu + ((a.u >> 16) & 1u);
  return (u16)(r >> 16);
}
DEVI float b2f(u16 h) {
  union { uint32_t u; float f; } a; a.u = ((uint32_t)h) << 16; return a.f;
}

// ---------------- fp32 -> bf16 transposed weight conversion (K x N -> Npad x K)
__global__ void k_wcvt(const float* __restrict__ in, u16* __restrict__ out,
                       int K, int N, int Npad) {
  __shared__ float t[32][33];
  int bk = blockIdx.x * 32, bn = blockIdx.y * 32;
  int tx = threadIdx.x, ty = threadIdx.y;
  #pragma unroll
  for (int i = ty; i < 32; i += 8) {
    int n = bn + tx;
    t[i][tx] = (n < N) ? in[(size_t)(bk + i) * N + n] : 0.f;
  }
  __syncthreads();
  #pragma unroll
  for (int i = ty; i < 32; i += 8) {
    int n = bn + i;
    out[(size_t)n * K + bk + tx] = f2b(t[tx][i]);
  }
}

// ---------------- embedding gather
__global__ void k_embed(const int* __restrict__ tok, const float* __restrict__ emb,
                        float* __restrict__ h) {
  int m = blockIdx.x;
  int t = tok[m];
  const float4* src = (const float4*)(emb + (size_t)t * Dd);
  float4* dst = (float4*)(h + (size_t)m * Dd);
  dst[threadIdx.x] = src[threadIdx.x];
}

// ---------------- rmsnorm: f32 (stride inStride) -> bf16 (stride K)
__global__ void k_rms(const float* __restrict__ in, int inStride,
                      const float* __restrict__ w, u16* __restrict__ out, int K) {
  int m = blockIdx.x;
  const float* x = in + (size_t)m * inStride;
  float ss = 0.f;
  for (int i = threadIdx.x; i < K; i += 256) { float v = x[i]; ss += v * v; }
  #pragma unroll
  for (int off = 32; off; off >>= 1) ss += __shfl_xor(ss, off);
  __shared__ float red[4];
  if ((threadIdx.x & 63) == 0) red[threadIdx.x >> 6] = ss;
  __syncthreads();
  float r = rsqrtf((red[0] + red[1] + red[2] + red[3]) / (float)K + EPSF);
  for (int i = threadIdx.x; i < K; i += 256)
    out[(size_t)m * K + i] = f2b(x[i] * r * w[i]);
}

// ---------------- bias concat for fused down-proj (288 kv | pad | 384 q)
__global__ void k_biascat(const float* __restrict__ b1, const float* __restrict__ b2,
                          float* __restrict__ out) {
  int i = blockIdx.x * 256 + threadIdx.x;  // 0..767
  float v = 0.f;
  if (i < 288) v = b1[i];
  else if (i >= 384) v = b2[i - 384];
  out[i] = v;
}

// ---------------- build Q (rope on cols 64..95, *QSCALE, pad to 128)
__global__ void k_buildq(const float* __restrict__ qf, u16* __restrict__ Q) {
  int s = blockIdx.x, bh = blockIdx.y;
  int b = bh >> 4, h = bh & 15;
  int d = threadIdx.x;
  const float* row = qf + (size_t)(b * Ss + s) * (Hh * 96) + h * 96;
  float v = 0.f;
  if (d < 64) v = row[d];
  else if (d < 96) {
    int j = d - 64;
    int jj = j & 15;
    float theta = __expf(-(float)jj * LOG1E4_16);
    float ang = (float)s * theta;
    float sn, cs; __sincosf(ang, &sn, &cs);
    float x = row[64 + j];
    float o = row[64 + (j ^ 16)];
    v = x * cs + ((j < 16) ? -o : o) * sn;
  }
  Q[((size_t)bh * Ss + s) * QKD + d] = f2b(v * QSCALE);
}

// ---------------- build K (k from kv, roped k_rope from fused ckvq, bcast over heads)
__global__ void k_buildk(const float* __restrict__ kv, const float* __restrict__ ckvq,
                         u16* __restrict__ Kb) {
  int s = blockIdx.x, bh = blockIdx.y;
  int b = bh >> 4, h = bh & 15;
  int d = threadIdx.x;
  int m = b * Ss + s;
  float v = 0.f;
  if (d < 64) v = kv[(size_t)m * 2048 + h * 128 + d];
  else if (d < 96) {
    int j = d - 64;
    int jj = j & 15;
    float theta = __expf(-(float)jj * LOG1E4_16);
    float ang = (float)s * theta;
    float sn, cs; __sincosf(ang, &sn, &cs);
    const float* rr = ckvq + (size_t)m * 768 + 256;
    float x = rr[j];
    float o = rr[j ^ 16];
    v = x * cs + ((j < 16) ? -o : o) * sn;
  }
  Kb[((size_t)bh * Ss + s) * QKD + d] = f2b(v);
}

// ---------------- build V^T (per head: [64 rows used of 128][1024]), bf16
__global__ void k_buildvt(const float* __restrict__ kv, u16* __restrict__ Vt) {
  __shared__ float t[32][33];
  int bh = blockIdx.x, s0 = blockIdx.y * 32, d0 = blockIdx.z * 32;
  int b = bh >> 4, h = bh & 15;
  int tx = threadIdx.x, ty = threadIdx.y;
  #pragma unroll
  for (int i = ty; i < 32; i += 8) {
    int s = s0 + i, d = d0 + tx;
    t[i][tx] = kv[(size_t)(b * Ss + s) * 2048 + h * 128 + 64 + d];
  }
  __syncthreads();
  #pragma unroll
  for (int i = ty; i < 32; i += 8) {
    int d = d0 + i, s = s0 + tx;
    Vt[((size_t)bh * 128 + d) * Ss + s] = f2b(t[tx][i]);
  }
}

// ---------------- in-place row softmax, causal by index (upper region may be garbage)
__global__ void k_softmax(u16* __restrict__ sc) {
  int gr = blockIdx.x * 4 + (threadIdx.x >> 6);
  int row = gr & 1023;               // position within sequence
  int lane = threadIdx.x & 63;
  u16* p = sc + (size_t)gr * 1024;
  u16x8 h0 = *(const u16x8*)(p + lane * 8);
  u16x8 h1 = *(const u16x8*)(p + 512 + lane * 8);
  float v[16];
  #pragma unroll
  for (int i = 0; i < 8; i++) {
    int c0 = lane * 8 + i, c1 = 512 + lane * 8 + i;
    v[i]     = (c0 <= row) ? b2f(h0[i]) : NEG;
    v[8 + i] = (c1 <= row) ? b2f(h1[i]) : NEG;
  }
  float mx = v[0];
  #pragma unroll
  for (int i = 1; i < 16; i++) mx = fmaxf(mx, v[i]);
  #pragma unroll
  for (int off = 32; off; off >>= 1) mx = fmaxf(mx, __shfl_xor(mx, off));
  float sum = 0.f;
  #pragma unroll
  for (int i = 0; i < 16; i++) { v[i] = __expf(v[i] - mx); sum += v[i]; }
  #pragma unroll
  for (int off = 32; off; off >>= 1) sum += __shfl_xor(sum, off);
  float inv = 1.f / sum;
  #pragma unroll
  for (int i = 0; i < 8; i++) { h0[i] = f2b(v[i] * inv); h1[i] = f2b(v[8 + i] * inv); }
  *(u16x8*)(p + lane * 8) = h0;
  *(u16x8*)(p + 512 + lane * 8) = h1;
}

// ---------------- bf16 MFMA GEMM, A: MxK row-major, Bt: Npad x K row-major
// MODE 0: f32 C = acc + bias
// MODE 1: f32 C += acc + bias (residual)
// MODE 2: bf16 scores, causal, batched, triangular tile launch (blockIdx.x = tri id)
// MODE 3: bf16 PV -> attn scatter [(b*S+row)*D + h*64 + col]   (BN=64)
#define GAS __attribute__((address_space(1)))
#define LAS __attribute__((address_space(3)))
DEVI void gll16(const void* g, void* l) {
  __builtin_amdgcn_global_load_lds((GAS const void*)g, (LAS void*)l, 16, 0, 0);
}

template <int MODE, int BN, bool SWZ>
__global__ __launch_bounds__(256) void k_gemm(
    const u16* __restrict__ A, const u16* __restrict__ Bt,
    const float* __restrict__ bias, void* __restrict__ C,
    int N, int K, long sA, long sB, long sC) {
  __shared__ u16 lA[128 * 32];
  __shared__ u16 lB[BN * 32];
  const int tid = threadIdx.x;
  const int bz = blockIdx.z;

  int bx, by;
  if (MODE == 2) {
    // triangular decode: tile t -> (bx, by), by <= bx
    int t = blockIdx.x;
    bx = (int)((sqrtf(8.f * t + 1.f) - 1.f) * 0.5f);
    while ((bx + 1) * (bx + 2) / 2 <= t) ++bx;
    while (bx * (bx + 1) / 2 > t) --bx;
    by = t - bx * (bx + 1) / 2;
  } else if (SWZ) {
    int gx = gridDim.x;
    int nwg = gx * gridDim.y;
    int f = blockIdx.y * gx + blockIdx.x;
    int f2 = (f & 7) * (nwg >> 3) + (f >> 3);
    bx = f2 % gx; by = f2 / gx;
  } else {
    bx = blockIdx.x; by = blockIdx.y;
  }
  const long m0 = (long)bx * 128, n0 = (long)by * BN;

  const u16* Az = A + (size_t)bz * sA;
  const u16* Bz = Bt + (size_t)bz * sB;
  const int srow = tid >> 2;
  const int scol = (tid & 3) << 3;
  const u16* a0 = Az + (m0 + srow) * (long)K + scol;
  const u16* b0 = Bz + (n0 + srow) * (long)K + scol;
  const long rstep = 64L * K;

  const int lane = tid & 63, wid = tid >> 6;
  constexpr int WR = (BN == 128) ? 64 : 32;   // rows per wave
  constexpr int MI = WR / 16;
  const int wm = (BN == 128) ? (wid >> 1) * 64 : wid * 32;
  const int wn = (BN == 128) ? (wid & 1) * 64 : 0;
  const int fr = lane & 15, kg = (lane >> 4) * 8;

  f32x4 acc[MI][4] = {};

  for (int kk = 0; kk < K; kk += 32) {
    gll16(a0 + kk, lA + tid * 8);
    gll16(a0 + rstep + kk, lA + 2048 + tid * 8);
    gll16(b0 + kk, lB + tid * 8);
    if (BN == 128) gll16(b0 + rstep + kk, lB + 2048 + tid * 8);
    __syncthreads();
    bf16x8 af[MI], bfr[4];
    #pragma unroll
    for (int i = 0; i < MI; i++) af[i] = *(const bf16x8*)&lA[(wm + i * 16 + fr) * 32 + kg];
    #pragma unroll
    for (int j = 0; j < 4; j++) bfr[j] = *(const bf16x8*)&lB[(wn + j * 16 + fr) * 32 + kg];
    #pragma unroll
    for (int i = 0; i < MI; i++)
      #pragma unroll
      for (int j = 0; j < 4; j++)
        acc[i][j] = __builtin_amdgcn_mfma_f32_16x16x32_bf16(af[i], bfr[j], acc[i][j], 0, 0, 0);
    __syncthreads();
  }

  const int rb = wm + ((lane >> 4) << 2);
  const int cb = wn + (lane & 15);
  #pragma unroll
  for (int j = 0; j < 4; j++) {
    long gcol = n0 + cb + j * 16;
    float bs = 0.f;
    if ((MODE == 0 || MODE == 1) && gcol < N) bs = bias[gcol];
    #pragma unroll
    for (int i = 0; i < MI; i++) {
      #pragma unroll
      for (int r = 0; r < 4; r++) {
        long grow = m0 + rb + i * 16 + r;
        float val = acc[i][j][r];
        if (MODE == 0) {
          if (gcol < N) ((float*)C)[grow * N + gcol] = val + bs;
        } else if (MODE == 1) {
          if (gcol < N) { float* p = (float*)C + grow * N + gcol; *p += val + bs; }
        } else if (MODE == 2) {
          u16* out = (u16*)C + (size_t)bz * sC;
          out[grow * 1024 + gcol] = f2b((gcol <= grow) ? val : NEG);
        } else {
          int b = bz >> 4, h = bz & 15;
          ((u16*)C)[((size_t)(b * Ss) + grow) * Dd + h * 64 + gcol] = f2b(val);
        }
      }
    }
  }
}

// ---------------- silu gate: uv (2048 x 5632 f32) -> gated bf16 (2048 x 2816)
__global__ void k_silu(const float* __restrict__ uv, u16* __restrict__ g) {
  int n = blockIdx.x * 256 + threadIdx.x;
  int m = blockIdx.y;
  float u = uv[(size_t)m * 5632 + n];
  float x = uv[(size_t)m * 5632 + 2816 + n];
  float sg = 1.f / (1.f + __expf(-x));
  g[(size_t)m * 2816 + n] = f2b(u * x * sg);
}

extern "C" void kernel_launch(void* const* d_in, const int* in_sizes, int n_in,
                              void* d_out, int out_size, void* d_ws, size_t ws_size,
                              hipStream_t stream) {
  (void)in_sizes; (void)n_in; (void)out_size; (void)ws_size;
  const int*   tokens    = (const int*)  d_in[0];
  const float* embed     = (const float*)d_in[1];
  const float* w_kv_down = (const float*)d_in[2];
  const float* b_kv_down = (const float*)d_in[3];
  const float* w_q_down  = (const float*)d_in[4];
  const float* b_q_down  = (const float*)d_in[5];
  const float* w_kv_up   = (const float*)d_in[6];
  const float* b_kv_up   = (const float*)d_in[7];
  const float* w_q_up    = (const float*)d_in[8];
  const float* b_q_up    = (const float*)d_in[9];
  const float* w_o       = (const float*)d_in[10];
  const float* b_o       = (const float*)d_in[11];
  const float* kv_norm_w = (const float*)d_in[12];
  const float* q_norm_w  = (const float*)d_in[13];
  const float* norm1_w   = (const float*)d_in[14];
  const float* norm2_w   = (const float*)d_in[15];
  const float* w_in      = (const float*)d_in[16];
  const float* b_in      = (const float*)d_in[17];
  const float* w_out     = (const float*)d_in[18];
  const float* b_out     = (const float*)d_in[19];
  const float* norm_f_w  = (const float*)d_in[20];
  const float* w_head    = (const float*)d_in[21];
  const float* b_head    = (const float*)d_in[22];

  char* base = (char*)d_ws;
  size_t off = 0;
  auto alloc = [&](size_t bytes) -> void* {
    void* p = base + off;
    off += (bytes + 255) & ~(size_t)255;
    return p;
  };
  // shared per-layer transposed-weight arena (head: 32000x1024 bf16 = 65.5MB)
  u16* warena = (u16*)alloc((size_t)32000 * 1024 * 2);
  u16* wT_dq    = warena;                        // 768 x 1024 (kv_down 0..287 | pad | q_down 384..767)
  u16* wT_kvup  = wT_dq   + 768 * 1024;          // 2048 x 256
  u16* wT_qup   = wT_kvup + 2048 * 256;          // 1536 x 384
  u16* wT_o     = wT_qup  + 1536 * 384;          // 1024 x 1024
  u16* wT_in    = wT_o    + 1024 * 1024;         // 5632 x 1024
  u16* wT_out   = wT_in   + 5632 * 1024;         // 1024 x 2816

  float* h     = (float*)alloc((size_t)Mm * 1024 * 4);
  u16*   xn    = (u16*)  alloc((size_t)Mm * 1024 * 2);
  float* ckvq  = (float*)alloc((size_t)Mm * 768 * 4);   // fused down-proj out
  float* bdq   = (float*)alloc(768 * 4);
  u16*   ckvn  = (u16*)  alloc((size_t)Mm * 256 * 2);
  float* kv    = (float*)alloc((size_t)Mm * 2048 * 4);
  u16*   qdn   = (u16*)  alloc((size_t)Mm * 384 * 2);
  float* qf    = (float*)alloc((size_t)Mm * 1536 * 4);
  u16*   Qb    = (u16*)  alloc((size_t)32 * 1024 * QKD * 2);
  u16*   Kb    = (u16*)  alloc((size_t)32 * 1024 * QKD * 2);
  u16*   Vt    = (u16*)  alloc((size_t)32 * 128 * 1024 * 2);
  // scores (67MB bf16) aliased with uv (46MB f32): disjoint lifetimes in a layer
  void* bigbuf = alloc((size_t)32 * 1024 * 1024 * 2);
  u16*   sc    = (u16*)bigbuf;
  float* uvb   = (float*)bigbuf;
  u16*   attn  = (u16*)  alloc((size_t)Mm * 1024 * 2);
  u16*   gate  = (u16*)  alloc((size_t)Mm * 2816 * 2);

  dim3 tb(32, 8);
  auto cvt = [&](const float* src, u16* dst, int K, int N, int Npad) {
    dim3 gg(K / 32, Npad / 32);
    k_wcvt<<<gg, tb, 0, stream>>>(src, dst, K, N, Npad);
  };

  k_embed<<<Mm, 256, 0, stream>>>(tokens, embed, h);

  for (int l = 0; l < 4; l++) {
    cvt(w_kv_down + (size_t)l * 1024 * 288,  wT_dq,            1024, 288, 384);
    cvt(w_q_down  + (size_t)l * 1024 * 384,  wT_dq + 384*1024, 1024, 384, 384);
    cvt(w_kv_up   + (size_t)l * 256 * 2048,  wT_kvup,          256, 2048, 2048);
    cvt(w_q_up    + (size_t)l * 384 * 1536,  wT_qup,           384, 1536, 1536);
    cvt(w_o       + (size_t)l * 1024 * 1024, wT_o,             1024, 1024, 1024);
    cvt(w_in      + (size_t)l * 1024 * 5632, wT_in,            1024, 5632, 5632);
    cvt(w_out     + (size_t)l * 2816 * 1024, wT_out,           2816, 1024, 1024);
    k_biascat<<<3, 256, 0, stream>>>(b_kv_down + l * 288, b_q_down + l * 384, bdq);

    k_rms<<<Mm, 256, 0, stream>>>(h, 1024, norm1_w + l * 1024, xn, 1024);
    // fused kv_down + q_down: N=768
    k_gemm<0, 128, true><<<dim3(16, 6), 256, 0, stream>>>(xn, wT_dq, bdq,
                                                          ckvq, 768, 1024, 0, 0, 0);
    k_rms<<<Mm, 256, 0, stream>>>(ckvq, 768, kv_norm_w + l * 256, ckvn, 256);
    k_gemm<0, 128, true><<<dim3(16, 16), 256, 0, stream>>>(ckvn, wT_kvup, b_kv_up + l * 2048,
                                                           kv, 2048, 256, 0, 0, 0);
    k_rms<<<Mm, 256, 0, stream>>>(ckvq + 384, 768, q_norm_w + l * 384, qdn, 384);
    k_gemm<0, 128, true><<<dim3(16, 12), 256, 0, stream>>>(qdn, wT_qup, b_q_up + l * 1536,
                                                           qf, 1536, 384, 0, 0, 0);
    k_buildq<<<dim3(Ss, 32), 128, 0, stream>>>(qf, Qb);
    k_buildk<<<dim3(Ss, 32), 128, 0, stream>>>(kv, ckvq, Kb);
    k_buildvt<<<dim3(32, 32, 2), tb, 0, stream>>>(kv, Vt);
    // scores: triangular tiles only (36 per head), causal mask on diagonal tiles
    k_gemm<2, 128, false><<<dim3(36, 1, 32), 256, 0, stream>>>(Qb, Kb, nullptr, sc,
                                                               1024, 128, 1024L * 128,
                                                               1024L * 128, 1024L * 1024);
    k_softmax<<<(32 * 1024) / 4, 256, 0, stream>>>(sc);
    // PV: N=64 (no pad), per-(b,h), epilogue scatters into (B,S,H*64)
    k_gemm<3, 64, false><<<dim3(8, 1, 32), 256, 0, stream>>>(sc, Vt, nullptr, attn,
                                                             64, 1024, 1024L * 1024,
                                                             128L * 1024, 0);
    k_gemm<1, 128, true><<<dim3(16, 8), 256, 0, stream>>>(attn, wT_o, b_o + l * 1024,
                                                          h, 1024, 1024, 0, 0, 0);
    k_rms<<<Mm, 256, 0, stream>>>(h, 1024, norm2_w + l * 1024, xn, 1024);
    k_gemm<0, 128, true><<<dim3(16, 44), 256, 0, stream>>>(xn, wT_in, b_in + l * 5632,
                                                           uvb, 5632, 1024, 0, 0, 0);
    k_silu<<<dim3(11, Mm), 256, 0, stream>>>(uvb, gate);
    k_gemm<1, 128, true><<<dim3(16, 8), 256, 0, stream>>>(gate, wT_out, b_out + l * 1024,
                                                          h, 1024, 2816, 0, 0, 0);
  }

  k_rms<<<Mm, 256, 0, stream>>>(h, 1024, norm_f_w, xn, 1024);
  cvt(w_head, warena, 1024, 32000, 32000);
  k_gemm<0, 128, true><<<dim3(16, 250), 256, 0, stream>>>(xn, warena, b_head,
                                                          (float*)d_out, 32000, 1024, 0, 0, 0);
}